// Round 5
// baseline (38.119 us; speedup 1.0000x reference)
//
#include <hip/hip_runtime.h>
#include <hip/hip_bf16.h>

#define NBINS 32
#define LDS_STRIDE 200      // halfs; 400B row stride (16B-aligned rows, uniform bank spread on b128)
#define NTHREADS 192        // 3 waves; each wave owns K=64 of the 192-voxel chunk
#define NVOX 884736         // 96^3 = 4608 * 192
#define BPB 384             // blocks per batch -> grid 768 = exactly 3 blocks/CU
#define NCHUNKS 12          // 384 * 12 = 4608 slabs of 192 voxels, perfectly uniform
#define NSLOTS 16
#define TILE_HALVES (NBINS * LDS_STRIDE)   // 6400 halfs = 12.5 KB

typedef __attribute__((ext_vector_type(8))) _Float16 half8;
typedef __attribute__((ext_vector_type(16))) float f32x16;
typedef __attribute__((ext_vector_type(4))) int i32x4;

// Parzen: exponent in bin units: -2*(tt-b)^2.  6-tap asymmetric window
// [ki-3+(u>0) .. +5]: dropped tap has w <= e^-18 ~ 1.5e-8 (negligible).
// Thread owns LDS column `tid`; zeroes its own taps from 2 chunks ago (same
// ping-pong buffer) then writes new ones. Same-thread ds ops are ordered.
__device__ __forceinline__ void scatter_rewrite(_Float16* __restrict__ L, int tid, float x,
                                                int& kb_old, bool zero_old) {
    float tt = x * 31.0f;
    float kf = rintf(tt);
    int ki = (int)kf;
    float u = tt - kf;               // [-0.5, 0.5]
    int kb = ki - 3 + (u > 0.0f ? 1 : 0);
    if (zero_old) {
#pragma unroll
        for (int o = 0; o < 6; ++o) {
            int b = kb_old + o;
            if (b >= 0 && b < NBINS) L[b * LDS_STRIDE + tid] = (_Float16)0.0f;
        }
    }
    float w[6];
    float s = 0.0f;
#pragma unroll
    for (int o = 0; o < 6; ++o) {
        int b = kb + o;
        float d = tt - (float)b;
        float e = __expf(-2.0f * d * d);
        bool valid = (b >= 0) && (b < NBINS);
        e = valid ? e : 0.0f;
        w[o] = e;
        s += e;
    }
    float rinv = 1.0f / s;
#pragma unroll
    for (int o = 0; o < 6; ++o) {
        int b = kb + o;
        if (b >= 0 && b < NBINS)
            L[b * LDS_STRIDE + tid] = (_Float16)(w[o] * rinv);
    }
    kb_old = kb;
}

__device__ __forceinline__ void do_mfma(const _Float16* __restrict__ bufA,
                                        const _Float16* __restrict__ bufB,
                                        int frag_off, f32x16& acc) {
#pragma unroll
    for (int kb = 0; kb < 4; ++kb) {
        half8 af = *(const half8*)&bufA[frag_off + kb * 16];
        half8 bf = *(const half8*)&bufB[frag_off + kb * 16];
        acc = __builtin_amdgcn_mfma_f32_32x32x16_f16(af, bf, acc, 0, 0, 0);
    }
}

__global__ __launch_bounds__(NTHREADS, 2)
void mi_hist_kernel(const float* __restrict__ pred, const float* __restrict__ targ,
                    float* __restrict__ hist /* [NSLOTS][2][32][32] */) {
    // ping-pong: [parity][A tile | B tile]
    __shared__ __attribute__((aligned(16))) _Float16 smem[4 * TILE_HALVES];
    _Float16* A0 = smem;
    _Float16* B0 = smem + TILE_HALVES;
    _Float16* A1 = smem + 2 * TILE_HALVES;
    _Float16* B1 = smem + 3 * TILE_HALVES;

    const int tid = threadIdx.x;
    const int bx = blockIdx.x;
    const int batch = blockIdx.y;
    const float* p = pred + (size_t)batch * NVOX;
    const float* t = targ + (size_t)batch * NVOX;

    const int wid = tid >> 6;        // 0..2 ; wave covers K-window [wid*64, wid*64+64)
    const int lane = tid & 63;
    const int frag_off = (lane & 31) * LDS_STRIDE + wid * 64 + 8 * (lane >> 5);

    f32x16 acc;
#pragma unroll
    for (int r = 0; r < 16; ++r) acc[r] = 0.0f;

    // prologue: zero all 4 tiles once, prefetch chunk 0
    {
        i32x4 z = {0, 0, 0, 0};
        i32x4* zp = (i32x4*)smem;
        for (int i = tid; i < (4 * TILE_HALVES) / 8; i += NTHREADS) zp[i] = z;
    }
    float pv = p[(size_t)bx * NTHREADS + tid];
    float tv = t[(size_t)bx * NTHREADS + tid];
    int kbA0 = 0, kbB0 = 0, kbA1 = 0, kbB1 = 0;
    __syncthreads();

#pragma unroll 1
    for (int j = 0; j < NCHUNKS / 2; ++j) {
        // ---- chunk 2j (parity 0) ----
        {
            const int c = 2 * j;
            float pn = 0.0f, tn = 0.0f;
            if (c + 1 < NCHUNKS) {
                size_t v = ((size_t)(c + 1) * BPB + bx) * NTHREADS + tid;
                pn = p[v]; tn = t[v];
            }
            scatter_rewrite(A0, tid, pv, kbA0, j > 0);
            scatter_rewrite(B0, tid, tv, kbB0, j > 0);
            __syncthreads();             // scatter visible; also drains prior mfma reads
            do_mfma(A0, B0, frag_off, acc);
            pv = pn; tv = tn;
        }
        // ---- chunk 2j+1 (parity 1) ----
        {
            const int c = 2 * j + 1;
            float pn = 0.0f, tn = 0.0f;
            if (c + 1 < NCHUNKS) {
                size_t v = ((size_t)(c + 1) * BPB + bx) * NTHREADS + tid;
                pn = p[v]; tn = t[v];
            }
            scatter_rewrite(A1, tid, pv, kbA1, j > 0);
            scatter_rewrite(B1, tid, tv, kbB1, j > 0);
            __syncthreads();
            do_mfma(A1, B1, frag_off, acc);
            pv = pn; tv = tn;
        }
    }
    __syncthreads();                     // last mfma reads drained before smem reuse

    // block reduce: 3 waves hold K-split partials of the SAME 32x32.
    // C/D layout (32x32): col = lane&31, row = (reg&3) + 8*(reg>>2) + 4*(lane>>5)
    float* red = (float*)smem;           // 3 * 1024 floats = 12 KB
    const int col = lane & 31;
    const int rlo = 4 * (lane >> 5);
#pragma unroll
    for (int r = 0; r < 16; ++r) {
        int rowc = (r & 3) + 8 * (r >> 2) + rlo;
        red[wid * 1024 + rowc * 32 + col] = acc[r];
    }
    __syncthreads();
    float* H = hist + ((size_t)(bx & (NSLOTS - 1)) * 2 + batch) * 1024;
    for (int idx = tid; idx < 1024; idx += NTHREADS) {
        float s = red[idx] + red[1024 + idx] + red[2048 + idx];
        atomicAdd(&H[idx], s);
    }
}

__global__ void mi_reduce_kernel(const float* __restrict__ hist, float* __restrict__ out) {
    __shared__ float s_pab[2 * NBINS * NBINS];
    __shared__ double s_pa[2][NBINS];
    __shared__ double s_pb[2][NBINS];
    __shared__ double s_red[256];
    const int tid = threadIdx.x;
    const double invN = 1.0 / (double)NVOX;

    for (int g = tid; g < 512; g += 256) {
        float4 s = make_float4(0.f, 0.f, 0.f, 0.f);
        for (int sl = 0; sl < NSLOTS; ++sl) {
            float4 v = ((const float4*)hist)[sl * 512 + g];
            s.x += v.x; s.y += v.y; s.z += v.z; s.w += v.w;
        }
        ((float4*)s_pab)[g] = s;
    }
    __syncthreads();

    if (tid < 64) {
        int b = tid >> 5, i = tid & 31;
        double s = 0.0;
        for (int j = 0; j < NBINS; ++j) s += (double)s_pab[(b * NBINS + i) * NBINS + j];
        s_pa[b][i] = s * invN;
    } else if (tid < 128) {
        int t2 = tid - 64;
        int b = t2 >> 5, j = t2 & 31;
        double s = 0.0;
        for (int i = 0; i < NBINS; ++i) s += (double)s_pab[(b * NBINS + i) * NBINS + j];
        s_pb[b][j] = s * invN;
    }
    __syncthreads();

    double acc = 0.0;
    for (int idx = tid; idx < 2 * NBINS * NBINS; idx += 256) {
        int b = idx >> 10;
        int cell = idx & 1023;
        int i = cell >> 5, j = cell & 31;
        double pab = (double)s_pab[idx] * invN;
        double papb = s_pa[b][i] * s_pb[b][j];
        acc += pab * log((pab + 1e-7) / (papb + 1e-7) + 1e-7);
    }
    s_red[tid] = acc;
    __syncthreads();
    for (int s2 = 128; s2 > 0; s2 >>= 1) {
        if (tid < s2) s_red[tid] += s_red[tid + s2];
        __syncthreads();
    }
    if (tid == 0) out[0] = (float)(-0.5 * s_red[0]);
}

extern "C" void kernel_launch(void* const* d_in, const int* in_sizes, int n_in,
                              void* d_out, int out_size, void* d_ws, size_t ws_size,
                              hipStream_t stream) {
    const float* pred = (const float*)d_in[0];
    const float* targ = (const float*)d_in[1];
    float* hist = (float*)d_ws;
    float* out = (float*)d_out;

    hipMemsetAsync(hist, 0, NSLOTS * 2 * NBINS * NBINS * sizeof(float), stream);
    dim3 grid(BPB, 2);
    hipLaunchKernelGGL(mi_hist_kernel, grid, dim3(NTHREADS), 0, stream, pred, targ, hist);
    hipLaunchKernelGGL(mi_reduce_kernel, dim3(1), dim3(256), 0, stream, hist, out);
}

// Round 6
// 33.480 us; speedup vs baseline: 1.1386x; 1.1386x over previous
//
#include <hip/hip_runtime.h>
#include <hip/hip_bf16.h>

#define NBINS 32
#define CHUNK 128           // voxels per chunk per block
#define STR 136             // halfs per tile row (128 + 8 pad) -> 272B stride
#define TILE_HALVES (NBINS * STR)   // 4352 halfs = 8704 B per tile
#define NTHREADS 256
#define NVOX 884736         // 96^3 = 6912 * 128
#define BPB 512             // blocks per batch -> grid (512,2) = 1024 = exactly 4/CU
#define NSLOTS 8

typedef __attribute__((ext_vector_type(8))) _Float16 half8;
typedef __attribute__((ext_vector_type(16))) float f32x16;
typedef __attribute__((ext_vector_type(4))) int i32x4;

// Parzen, 6-tap asymmetric window [ki-3+(u>0) .. +5] (identical math to the
// validated R4/R5 kernels; dropped tap <= e^-18). All VALU incl. fp16 cvt done
// here, OUTSIDE the barrier-bounded region.
__device__ __forceinline__ void compute_w(float x, int& kb, _Float16* wq) {
    float tt = x * 31.0f;
    float kf = rintf(tt);
    int ki = (int)kf;
    float u = tt - kf;               // [-0.5, 0.5]
    kb = ki - 3 + (u > 0.0f ? 1 : 0);
    float w[6];
    float s = 0.0f;
#pragma unroll
    for (int o = 0; o < 6; ++o) {
        int b = kb + o;
        float d = tt - (float)b;
        float e = __expf(-2.0f * d * d);
        bool valid = (b >= 0) && (b < NBINS);
        e = valid ? e : 0.0f;
        w[o] = e;
        s += e;
    }
    float rinv = 1.0f / s;
#pragma unroll
    for (int o = 0; o < 6; ++o) wq[o] = (_Float16)(w[o] * rinv);
}

// Thread owns column `col` of ONE tile: zero its taps from 2 chunks ago (same
// parity buffer), write new ones. Same-thread ds ops are ordered.
__device__ __forceinline__ void scatter(_Float16* __restrict__ L, int col, int kb_new,
                                        const _Float16* wq, int kb_old, bool zero_old) {
    if (zero_old) {
#pragma unroll
        for (int o = 0; o < 6; ++o) {
            int b = kb_old + o;
            if (b >= 0 && b < NBINS) L[b * STR + col] = (_Float16)0.0f;
        }
    }
#pragma unroll
    for (int o = 0; o < 6; ++o) {
        int b = kb_new + o;
        if (b >= 0 && b < NBINS) L[b * STR + col] = wq[o];
    }
}

__global__ __launch_bounds__(NTHREADS, 4)
void mi_hist_kernel(const float* __restrict__ pred, const float* __restrict__ targ,
                    float* __restrict__ hist /* [NSLOTS][2][32][32] */) {
    // ping-pong buffers, each = A tile + B tile for 128 voxels
    __shared__ __attribute__((aligned(16))) _Float16 smem[4 * TILE_HALVES];

    const int tid = threadIdx.x;
    const int bx = blockIdx.x;
    const int batch = blockIdx.y;
    const int col = tid & 127;
    const bool isB = tid >= 128;                    // threads 0-127: pred tile, 128-255: targ tile
    const float* src = (isB ? targ : pred) + (size_t)batch * NVOX;
    const int tile_off = isB ? TILE_HALVES : 0;

    const int wid = tid >> 6;
    const int lane = tid & 63;
    // mfma_f32_32x32x16_f16: row(col)=lane&31, k = 8*(lane>>5)+j. Wave wid owns K [wid*32, wid*32+32).
    const int frag = (lane & 31) * STR + wid * 32 + 8 * (lane >> 5);

    // 6912 slabs/batch: c<=12 all 512 blocks, c=13 only bx<256. Block-uniform.
    const int nchunks = (bx < 256) ? 14 : 13;

    f32x16 acc;
#pragma unroll
    for (int r = 0; r < 16; ++r) acc[r] = 0.0f;

    // prologue: zero both buffers, load chunk 0
    {
        i32x4 z = {0, 0, 0, 0};
        i32x4* zp = (i32x4*)smem;
        for (int i = tid; i < (4 * TILE_HALVES) / 8; i += NTHREADS) zp[i] = z;
    }
    float x = src[(size_t)bx * CHUNK + col];
    int kb_old[2] = {0, 0};
    __syncthreads();

#pragma unroll 1
    for (int c = 0; c < nchunks; ++c) {
        const int q = c & 1;
        _Float16 wq[6];
        int kb;
        compute_w(x, kb, wq);                        // VALU, outside barrier region
        if (c + 1 < nchunks) {                       // prefetch next chunk
            x = src[((size_t)(c + 1) * BPB + bx) * CHUNK + col];
        }
        __syncthreads();
        // scatter chunk c into P[q]  ||  mfma chunk c-1 from P[q^1] (different buffer)
        scatter(smem + q * 2 * TILE_HALVES + tile_off, col, kb, wq, kb_old[q], c >= 2);
        kb_old[q] = kb;
        if (c >= 1) {
            const _Float16* Pp = smem + (q ^ 1) * 2 * TILE_HALVES;
#pragma unroll
            for (int kk = 0; kk < 2; ++kk) {
                half8 af = *(const half8*)&Pp[frag + kk * 16];
                half8 bf = *(const half8*)&Pp[TILE_HALVES + frag + kk * 16];
                acc = __builtin_amdgcn_mfma_f32_32x32x16_f16(af, bf, acc, 0, 0, 0);
            }
        }
    }
    __syncthreads();
    {   // epilogue: mfma of the last chunk
        const int q = (nchunks - 1) & 1;
        const _Float16* Pp = smem + q * 2 * TILE_HALVES;
#pragma unroll
        for (int kk = 0; kk < 2; ++kk) {
            half8 af = *(const half8*)&Pp[frag + kk * 16];
            half8 bf = *(const half8*)&Pp[TILE_HALVES + frag + kk * 16];
            acc = __builtin_amdgcn_mfma_f32_32x32x16_f16(af, bf, acc, 0, 0, 0);
        }
    }
    __syncthreads();                                 // all mfma reads done before smem reuse

    // block reduce: 4 waves hold K-split partials of the SAME 32x32.
    // C/D layout (32x32): col = lane&31, row = (reg&3) + 8*(reg>>2) + 4*(lane>>5)
    float* red = (float*)smem;                       // 4 * 1024 floats = 16 KB
    const int colc = lane & 31;
    const int rlo = 4 * (lane >> 5);
#pragma unroll
    for (int r = 0; r < 16; ++r) {
        int rowc = (r & 3) + 8 * (r >> 2) + rlo;
        red[wid * 1024 + rowc * 32 + colc] = acc[r];
    }
    __syncthreads();
    float* H = hist + ((size_t)(bx & (NSLOTS - 1)) * 2 + batch) * 1024;
    for (int idx = tid; idx < 1024; idx += NTHREADS) {
        float s = red[idx] + red[1024 + idx] + red[2048 + idx] + red[3072 + idx];
        atomicAdd(&H[idx], s);
    }
}

__global__ void mi_reduce_kernel(const float* __restrict__ hist, float* __restrict__ out) {
    __shared__ float s_pab[2 * NBINS * NBINS];
    __shared__ double s_pa[2][NBINS];
    __shared__ double s_pb[2][NBINS];
    __shared__ double s_red[256];
    const int tid = threadIdx.x;
    const double invN = 1.0 / (double)NVOX;

    for (int g = tid; g < 512; g += 256) {
        float4 s = make_float4(0.f, 0.f, 0.f, 0.f);
        for (int sl = 0; sl < NSLOTS; ++sl) {
            float4 v = ((const float4*)hist)[sl * 512 + g];
            s.x += v.x; s.y += v.y; s.z += v.z; s.w += v.w;
        }
        ((float4*)s_pab)[g] = s;
    }
    __syncthreads();

    if (tid < 64) {
        int b = tid >> 5, i = tid & 31;
        double s = 0.0;
        for (int j = 0; j < NBINS; ++j) s += (double)s_pab[(b * NBINS + i) * NBINS + j];
        s_pa[b][i] = s * invN;
    } else if (tid < 128) {
        int t2 = tid - 64;
        int b = t2 >> 5, j = t2 & 31;
        double s = 0.0;
        for (int i = 0; i < NBINS; ++i) s += (double)s_pab[(b * NBINS + i) * NBINS + j];
        s_pb[b][j] = s * invN;
    }
    __syncthreads();

    double acc = 0.0;
    for (int idx = tid; idx < 2 * NBINS * NBINS; idx += 256) {
        int b = idx >> 10;
        int cell = idx & 1023;
        int i = cell >> 5, j = cell & 31;
        double pab = (double)s_pab[idx] * invN;
        double papb = s_pa[b][i] * s_pb[b][j];
        acc += pab * log((pab + 1e-7) / (papb + 1e-7) + 1e-7);
    }
    s_red[tid] = acc;
    __syncthreads();
    for (int s2 = 128; s2 > 0; s2 >>= 1) {
        if (tid < s2) s_red[tid] += s_red[tid + s2];
        __syncthreads();
    }
    if (tid == 0) out[0] = (float)(-0.5 * s_red[0]);
}

extern "C" void kernel_launch(void* const* d_in, const int* in_sizes, int n_in,
                              void* d_out, int out_size, void* d_ws, size_t ws_size,
                              hipStream_t stream) {
    const float* pred = (const float*)d_in[0];
    const float* targ = (const float*)d_in[1];
    float* hist = (float*)d_ws;
    float* out = (float*)d_out;

    hipMemsetAsync(hist, 0, NSLOTS * 2 * NBINS * NBINS * sizeof(float), stream);
    dim3 grid(BPB, 2);
    hipLaunchKernelGGL(mi_hist_kernel, grid, dim3(NTHREADS), 0, stream, pred, targ, hist);
    hipLaunchKernelGGL(mi_reduce_kernel, dim3(1), dim3(256), 0, stream, hist, out);
}

// Round 7
// 31.047 us; speedup vs baseline: 1.2278x; 1.0784x over previous
//
#include <hip/hip_runtime.h>
#include <hip/hip_bf16.h>

#define NBINS 32
#define CHUNK 128           // voxels per chunk per block
#define NROWS 34            // bins clamped to [-1,32] then +1 -> rows 0..33; rows 1..32 = bins 0..31
#define STR 136             // halfs per row; 272B stride, 16B-aligned, bank-uniform b128 reads
#define TILE_HALVES (NROWS * STR)   // 4624 halfs = 9248 B
#define NTHREADS 256
#define NVOX 884736         // 96^3 = 6912 * 128
#define BPB 512             // grid (512,2) = 1024 blocks = exactly 4/CU
#define NSLOTS 8

typedef __attribute__((ext_vector_type(8))) _Float16 half8;
typedef __attribute__((ext_vector_type(16))) float f32x16;
typedef __attribute__((ext_vector_type(4))) int i32x4;

// Parzen 6-tap window — BIT-IDENTICAL math to the validated R4-R6 kernels.
__device__ __forceinline__ void compute_w(float x, int& kb, _Float16* wq) {
    float tt = x * 31.0f;
    float kf = rintf(tt);
    int ki = (int)kf;
    float u = tt - kf;               // [-0.5, 0.5]
    kb = ki - 3 + (u > 0.0f ? 1 : 0);
    float w[6];
    float s = 0.0f;
#pragma unroll
    for (int o = 0; o < 6; ++o) {
        int b = kb + o;
        float d = tt - (float)b;
        float e = __expf(-2.0f * d * d);
        e = ((unsigned)b < NBINS) ? e : 0.0f;   // same predicate as (b>=0 && b<32)
        w[o] = e;
        s += e;
    }
    float rinv = 1.0f / s;
#pragma unroll
    for (int o = 0; o < 6; ++o) wq[o] = (_Float16)(w[o] * rinv);
}

// Unconditional clamped writes: out-of-range taps land in garbage rows 0/33 (never read).
__device__ __forceinline__ void zero6(_Float16* __restrict__ L, int col, int kb) {
#pragma unroll
    for (int o = 0; o < 6; ++o) {
        int r = min(max(kb + o, -1), 32) + 1;
        L[r * STR + col] = (_Float16)0.0f;
    }
}
__device__ __forceinline__ void scatter6(_Float16* __restrict__ L, int col, int kb,
                                         const _Float16* wq) {
#pragma unroll
    for (int o = 0; o < 6; ++o) {
        int r = min(max(kb + o, -1), 32) + 1;
        L[r * STR + col] = wq[o];
    }
}

__global__ __launch_bounds__(NTHREADS, 4)
void mi_hist_kernel(const float* __restrict__ pred, const float* __restrict__ targ,
                    float* __restrict__ hist /* [NSLOTS][2][32][32] */) {
    // ping-pong buffers P0/P1, each = A tile + B tile
    __shared__ __attribute__((aligned(16))) _Float16 smem[4 * TILE_HALVES];

    const int tid = threadIdx.x;
    const int bx = blockIdx.x;
    const int batch = blockIdx.y;
    const int col = tid & 127;
    const bool isB = tid >= 128;                 // 0-127: pred tile, 128-255: targ tile
    const float* src = (isB ? targ : pred) + (size_t)batch * NVOX;
    const int toff = isB ? TILE_HALVES : 0;

    const int wid = tid >> 6;
    const int lane = tid & 63;
    // mfma_f32_32x32x16_f16: row(col)=lane&31 (bin b -> LDS row b+1), wave wid owns K [wid*32,+32)
    const int frag = (1 + (lane & 31)) * STR + wid * 32 + 8 * (lane >> 5);

    // preload ALL chunk values -> no vmem in the main loop (barriers drain nothing)
    float xs[14];
#pragma unroll
    for (int c = 0; c < 13; ++c)
        xs[c] = src[((size_t)(c * BPB + bx)) * CHUNK + col];
    const bool extra = (bx < 256);               // 6912 = 512*13 + 256, block-uniform
    if (extra) xs[13] = src[((size_t)(13 * BPB + bx)) * CHUNK + col];

    // zero all 4 tiles once
    {
        i32x4 z = {0, 0, 0, 0};
        i32x4* zp = (i32x4*)smem;
#pragma unroll
        for (int i = 0; i < 10; ++i) {
            int idx = i * NTHREADS + tid;
            if (idx < (4 * TILE_HALVES) / 8) zp[idx] = z;
        }
    }

    f32x16 acc;
#pragma unroll
    for (int r = 0; r < 16; ++r) acc[r] = 0.0f;

    int kbo0 = 0, kbo1 = 0;

#define DO_MFMA(BASE) { \
        const _Float16* Pp = (BASE); \
        _Pragma("unroll") \
        for (int kk = 0; kk < 2; ++kk) { \
            half8 af = *(const half8*)&Pp[frag + kk * 16]; \
            half8 bf = *(const half8*)&Pp[TILE_HALVES + frag + kk * 16]; \
            acc = __builtin_amdgcn_mfma_f32_32x32x16_f16(af, bf, acc, 0, 0, 0); \
        } }

#pragma unroll
    for (int c = 0; c < 13; ++c) {
        _Float16 wq[6];
        int kb;
        compute_w(xs[c], kb, wq);                // VALU before barrier (overlaps prev MFMA phase)
        __syncthreads();                         // c=0: covers prologue zero-fill visibility
        _Float16* cur = smem + (c & 1) * 2 * TILE_HALVES + toff;
        if (c >= 2) zero6(cur, col, (c & 1) ? kbo1 : kbo0);   // stale taps from chunk c-2
        scatter6(cur, col, kb, wq);
        if (c & 1) kbo1 = kb; else kbo0 = kb;
        if (c >= 1) DO_MFMA(smem + (((c & 1) ^ 1) * 2) * TILE_HALVES);  // chunk c-1's buffer
    }
    if (extra) {                                 // chunk 13 (q=1), block-uniform branch
        _Float16 wq[6];
        int kb;
        compute_w(xs[13], kb, wq);
        __syncthreads();
        _Float16* cur = smem + 2 * TILE_HALVES + toff;
        zero6(cur, col, kbo1);
        scatter6(cur, col, kb, wq);
        DO_MFMA(smem);                           // chunk 12 (P0)
        __syncthreads();
        DO_MFMA(smem + 2 * TILE_HALVES);         // chunk 13 (P1)
    } else {
        __syncthreads();
        DO_MFMA(smem);                           // chunk 12 (P0)
    }
    __syncthreads();                             // all mfma reads done before smem reuse

    // block reduce: 4 waves hold K-split partials of the SAME 32x32.
    // C/D layout (32x32): col = lane&31, row = (reg&3) + 8*(reg>>2) + 4*(lane>>5)
    float* red = (float*)smem;                   // 4 * 1024 floats = 16 KB
    const int colc = lane & 31;
    const int rlo = 4 * (lane >> 5);
#pragma unroll
    for (int r = 0; r < 16; ++r) {
        int rowc = (r & 3) + 8 * (r >> 2) + rlo;
        red[wid * 1024 + rowc * 32 + colc] = acc[r];
    }
    __syncthreads();
    float* H = hist + ((size_t)(bx & (NSLOTS - 1)) * 2 + batch) * 1024;
    for (int idx = tid; idx < 1024; idx += NTHREADS) {
        float s = red[idx] + red[1024 + idx] + red[2048 + idx] + red[3072 + idx];
        atomicAdd(&H[idx], s);
    }
}

__global__ void mi_reduce_kernel(const float* __restrict__ hist, float* __restrict__ out) {
    __shared__ float s_pab[2 * NBINS * NBINS];
    __shared__ double s_pa[2][NBINS];
    __shared__ double s_pb[2][NBINS];
    __shared__ double s_red[256];
    const int tid = threadIdx.x;
    const double invN = 1.0 / (double)NVOX;

    for (int g = tid; g < 512; g += 256) {
        float4 s = make_float4(0.f, 0.f, 0.f, 0.f);
        for (int sl = 0; sl < NSLOTS; ++sl) {
            float4 v = ((const float4*)hist)[sl * 512 + g];
            s.x += v.x; s.y += v.y; s.z += v.z; s.w += v.w;
        }
        ((float4*)s_pab)[g] = s;
    }
    __syncthreads();

    if (tid < 64) {
        int b = tid >> 5, i = tid & 31;
        double s = 0.0;
        for (int j = 0; j < NBINS; ++j) s += (double)s_pab[(b * NBINS + i) * NBINS + j];
        s_pa[b][i] = s * invN;
    } else if (tid < 128) {
        int t2 = tid - 64;
        int b = t2 >> 5, j = t2 & 31;
        double s = 0.0;
        for (int i = 0; i < NBINS; ++i) s += (double)s_pab[(b * NBINS + i) * NBINS + j];
        s_pb[b][j] = s * invN;
    }
    __syncthreads();

    double acc = 0.0;
    for (int idx = tid; idx < 2 * NBINS * NBINS; idx += 256) {
        int b = idx >> 10;
        int cell = idx & 1023;
        int i = cell >> 5, j = cell & 31;
        double pab = (double)s_pab[idx] * invN;
        double papb = s_pa[b][i] * s_pb[b][j];
        acc += pab * log((pab + 1e-7) / (papb + 1e-7) + 1e-7);
    }
    s_red[tid] = acc;
    __syncthreads();
    for (int s2 = 128; s2 > 0; s2 >>= 1) {
        if (tid < s2) s_red[tid] += s_red[tid + s2];
        __syncthreads();
    }
    if (tid == 0) out[0] = (float)(-0.5 * s_red[0]);
}

extern "C" void kernel_launch(void* const* d_in, const int* in_sizes, int n_in,
                              void* d_out, int out_size, void* d_ws, size_t ws_size,
                              hipStream_t stream) {
    const float* pred = (const float*)d_in[0];
    const float* targ = (const float*)d_in[1];
    float* hist = (float*)d_ws;
    float* out = (float*)d_out;

    hipMemsetAsync(hist, 0, NSLOTS * 2 * NBINS * NBINS * sizeof(float), stream);
    dim3 grid(BPB, 2);
    hipLaunchKernelGGL(mi_hist_kernel, grid, dim3(NTHREADS), 0, stream, pred, targ, hist);
    hipLaunchKernelGGL(mi_reduce_kernel, dim3(1), dim3(256), 0, stream, hist, out);
}